// Round 8
// baseline (296.629 us; speedup 1.0000x reference)
//
#include <hip/hip_runtime.h>
#include <hip/hip_bf16.h>

constexpr int N = 10000;   // nodes
constexpr int D = 512;     // feature dim
constexpr int E = 160000;  // edges
constexpr int L = 3;       // layers
constexpr float EPS = 1e-5f;
constexpr int CHUNK = 128; // feature columns per chunk
constexpr int NCH = D / CHUNK;  // 4

typedef _Float16 half8 __attribute__((ext_vector_type(8)));
typedef _Float16 half2v __attribute__((ext_vector_type(2)));
typedef float floatx4 __attribute__((ext_vector_type(4)));

// async global->LDS, 16B per lane. LDS dest = wave-uniform base + lane*16.
__device__ __forceinline__ void glds16(const _Float16* g, _Float16* l) {
    __builtin_amdgcn_global_load_lds(
        (const __attribute__((address_space(1))) uint32_t*)(g),
        (__attribute__((address_space(3))) uint32_t*)(l),
        16, 0, 0);
}

// ---------------------------------------------------------------------------
// Mega setup: degrees + x fp32->f16 (chunked layout) + column stats + W^T.
// x16 layout: [NCH][N][CHUNK] f16.
// ---------------------------------------------------------------------------
constexpr int DEG_BLOCKS  = (E + 255) / 256;   // 625
constexpr int CONV_BLOCKS = 100;               // 100 rows each
constexpr int TW_BLOCKS   = L * 256;           // 768 (32x32 tiles)
constexpr int MEGA_BLOCKS = DEG_BLOCKS + CONV_BLOCKS + TW_BLOCKS;

__global__ __launch_bounds__(256) void mega_setup(
    const int* __restrict__ src, const int* __restrict__ dst,
    const float* __restrict__ x, const float* __restrict__ W,
    int* __restrict__ out_deg, int* __restrict__ in_deg,
    _Float16* __restrict__ x16, float* __restrict__ stats0,
    _Float16* __restrict__ Wt) {
    __shared__ float tb[32][33];
    int bid = blockIdx.x;
    int tid = threadIdx.x;
    if (bid < DEG_BLOCKS) {
        int e = bid * 256 + tid;
        if (e < E) {
            atomicAdd(&out_deg[src[e]], 1);
            atomicAdd(&in_deg[dst[e]], 1);
        }
    } else if (bid < DEG_BLOCKS + CONV_BLOCKS) {
        int b = bid - DEG_BLOCKS;
        int r0 = b * 100;
        int r1 = r0 + 100; if (r1 > N) r1 = N;
        int c2 = tid * 2;                 // global col pair
        int ch = c2 >> 7;                 // chunk
        int lc = c2 & 127;                // local col
        _Float16* xc = x16 + (size_t)ch * N * CHUNK;
        float s0 = 0.f, s1 = 0.f, q0 = 0.f, q1 = 0.f;
        for (int r = r0; r < r1; ++r) {
            float2 v = *(const float2*)(x + (size_t)r * D + c2);
            s0 += v.x; q0 += v.x * v.x;
            s1 += v.y; q1 += v.y * v.y;
            half2v h; h[0] = (_Float16)v.x; h[1] = (_Float16)v.y;
            *(half2v*)(xc + (size_t)r * CHUNK + lc) = h;
        }
        atomicAdd(&stats0[c2], s0);
        atomicAdd(&stats0[c2 + 1], s1);
        atomicAdd(&stats0[D + c2], q0);
        atomicAdd(&stats0[D + c2 + 1], q1);
    } else {
        int b = bid - DEG_BLOCKS - CONV_BLOCKS;  // 0..767
        int l = b >> 8;
        int t = b & 255;
        int k0 = (t >> 4) * 32, n0 = (t & 15) * 32;
        int tx = tid & 31, ty = tid >> 5;  // 32 x 8
        const float* Wl = W + (size_t)l * D * D;
        _Float16* Wtl = Wt + (size_t)l * D * D;
        for (int i = 0; i < 32; i += 8)
            tb[ty + i][tx] = Wl[(size_t)(k0 + ty + i) * D + n0 + tx];
        __syncthreads();
        for (int i = 0; i < 32; i += 8)
            Wtl[(size_t)(n0 + ty + i) * D + k0 + tx] = (_Float16)tb[tx][ty + i];
    }
}

// ---------------------------------------------------------------------------
// Single block: exclusive scan of in_deg -> off & cursor, plus both norms.
// ---------------------------------------------------------------------------
__global__ void scan_indeg(const int* __restrict__ in_deg,
                           const int* __restrict__ out_deg,
                           int* __restrict__ off, int* __restrict__ cursor,
                           float* __restrict__ src_norm, float* __restrict__ dst_norm) {
    __shared__ int lsum[1024];
    int t = threadIdx.x;
    const int chunk = (N + 1023) / 1024;
    int start = t * chunk;
    int end = start + chunk; if (end > N) end = N;
    int s = 0;
    for (int i = start; i < end; ++i) s += in_deg[i];
    lsum[t] = s;
    __syncthreads();
    for (int d = 1; d < 1024; d <<= 1) {
        int v = (t >= d) ? lsum[t - d] : 0;
        __syncthreads();
        lsum[t] += v;
        __syncthreads();
    }
    int excl = (t == 0) ? 0 : lsum[t - 1];
    for (int i = start; i < end; ++i) {
        off[i] = excl;
        cursor[i] = excl;
        excl += in_deg[i];
        int od = out_deg[i]; if (od < 1) od = 1;
        int id = in_deg[i];  if (id < 1) id = 1;
        src_norm[i] = rsqrtf((float)od);
        dst_norm[i] = rsqrtf((float)id);
    }
    if (t == 1023) off[N] = lsum[1023];
}

__global__ void csr_fill(const int* __restrict__ src, const int* __restrict__ dst,
                         int* __restrict__ cursor, int* __restrict__ csr_src) {
    int e = blockIdx.x * blockDim.x + threadIdx.x;
    if (e >= E) return;
    int d = dst[e];
    int pos = atomicAdd(&cursor[d], 1);
    csr_src[pos] = src[e];
}

// ---------------------------------------------------------------------------
// Fused BN + gather-aggregate, column-chunked with XCD pinning.
// Grid: (N/8)*8 blocks of 256. bid = g*8 + x; chunk = x>>1 (pinned to 2 XCDs
// under round-robin bid%8 -> XCD); sub = x&1; wave w handles node
// g*8 + sub*4 + w, 2 cols/lane within the chunk.
// ---------------------------------------------------------------------------
__global__ __launch_bounds__(256) void aggregate_bn(
    const _Float16* __restrict__ x, const int* __restrict__ off,
    const int* __restrict__ csr_src, const float* __restrict__ src_norm,
    const float* __restrict__ dst_norm, const float* __restrict__ stats,
    const float* __restrict__ gamma, const float* __restrict__ beta,
    _Float16* __restrict__ agg) {
    int bid = blockIdx.x;
    int g = bid >> 3;
    int xx = bid & 7;
    int ch = xx >> 1;
    int sub = xx & 1;
    int wave = threadIdx.x >> 6;
    int lane = threadIdx.x & 63;
    int n = g * 8 + sub * 4 + wave;  // N divisible by 8 -> always valid
    int lc = lane * 2;               // local col in chunk
    int gc = ch * CHUNK + lc;        // global col

    const _Float16* xc = x + (size_t)ch * N * CHUNK;
    _Float16* ac = agg + (size_t)ch * N * CHUNK;

    float scale[2], shift[2];
    const float invN = 1.0f / (float)N;
    for (int i = 0; i < 2; ++i) {
        int c = gc + i;
        float mu = stats[c] * invN;
        float var = stats[D + c] * invN - mu * mu;
        float sc = gamma[c] * rsqrtf(var + EPS);
        scale[i] = sc;
        shift[i] = beta[c] - mu * sc;
    }

    int e0 = off[n], e1 = off[n + 1];
    float a[2] = {}, a2[2] = {};
    float t = 0.f;
    int e = e0;
    for (; e + 4 <= e1; e += 4) {
        int s0 = csr_src[e];
        int s1 = csr_src[e + 1];
        int s2 = csr_src[e + 2];
        int s3 = csr_src[e + 3];
        float n0 = src_norm[s0];
        float n1 = src_norm[s1];
        float n2 = src_norm[s2];
        float n3 = src_norm[s3];
        half2v v0 = *(const half2v*)(xc + (size_t)s0 * CHUNK + lc);
        half2v v1 = *(const half2v*)(xc + (size_t)s1 * CHUNK + lc);
        half2v v2 = *(const half2v*)(xc + (size_t)s2 * CHUNK + lc);
        half2v v3 = *(const half2v*)(xc + (size_t)s3 * CHUNK + lc);
        t += (n0 + n1) + (n2 + n3);
        for (int k = 0; k < 2; ++k) {
            a[k]  += (float)v0[k] * n0 + (float)v2[k] * n2;
            a2[k] += (float)v1[k] * n1 + (float)v3[k] * n3;
        }
    }
    for (; e < e1; ++e) {
        int s0 = csr_src[e];
        float n0 = src_norm[s0];
        half2v v0 = *(const half2v*)(xc + (size_t)s0 * CHUNK + lc);
        t += n0;
        for (int k = 0; k < 2; ++k) a[k] += (float)v0[k] * n0;
    }
    float dn = dst_norm[n];
    half2v o;
    for (int i = 0; i < 2; ++i)
        o[i] = (_Float16)(dn * (scale[i] * (a[i] + a2[i]) + shift[i] * t));
    *(half2v*)(ac + (size_t)n * CHUNK + lc) = o;
}

// ---------------------------------------------------------------------------
// C = relu(A @ W + bias) via f16 MFMA with global_load_lds staging.
// A: chunked [NCH][M][CHUNK] f16.  Bt[n][k] = W[k][n], row-major 512.
// Block 256 = 4 waves; tile 128(M) x 128(N); BK=32.
// STATS=true also means: output written chunked f16 + next-layer stats.
// STATS=false: output row-major (OutT).
// ---------------------------------------------------------------------------
template <typename OutT, bool STATS>
__global__ __launch_bounds__(256) void mm_f16_relu(
    const _Float16* __restrict__ A, const _Float16* __restrict__ Bt,
    const float* __restrict__ bias, OutT* __restrict__ C, int M,
    float* __restrict__ stats) {
    __shared__ __align__(16) _Float16 As[128 * 32];
    __shared__ __align__(16) _Float16 Bs[128 * 32];
    const int tid  = threadIdx.x;
    const int wave = tid >> 6;
    const int lane = tid & 63;
    const int quad = lane >> 4;
    const int l16  = lane & 15;
    const int row0 = blockIdx.x * 128;
    const int col0 = blockIdx.y * 128;
    const int wm = (wave & 1) * 64;
    const int wn = (wave >> 1) * 64;
    const int sr = lane >> 2;
    const int sc = (lane & 3) * 8;

    int ar0 = row0 + wave * 32 + sr;
    int ar1 = ar0 + 16;
    if (ar0 >= M) ar0 = M - 1;
    if (ar1 >= M) ar1 = M - 1;
    const size_t aoff0 = (size_t)ar0 * CHUNK + sc;
    const size_t aoff1 = (size_t)ar1 * CHUNK + sc;
    const _Float16* gB0 = Bt + (size_t)(col0 + wave * 32 + sr) * D + sc;
    const _Float16* gB1 = Bt + (size_t)(col0 + wave * 32 + 16 + sr) * D + sc;
    _Float16* lA0 = As + (wave * 32) * 32;
    _Float16* lA1 = As + (wave * 32 + 16) * 32;
    _Float16* lB0 = Bs + (wave * 32) * 32;
    _Float16* lB1 = Bs + (wave * 32 + 16) * 32;

    floatx4 acc[4][4] = {};

    for (int k0 = 0; k0 < D; k0 += 32) {
        const _Float16* Ac = A + (size_t)(k0 >> 7) * M * CHUNK + (k0 & 127);
        __syncthreads();
        glds16(Ac + aoff0, lA0);
        glds16(Ac + aoff1, lA1);
        glds16(gB0 + k0, lB0);
        glds16(gB1 + k0, lB1);
        __syncthreads();  // compiler inserts vmcnt(0) drain here
        half8 af[4], bf[4];
        for (int i = 0; i < 4; ++i)
            af[i] = *(const half8*)(As + (wm + i * 16 + l16) * 32 + quad * 8);
        for (int j = 0; j < 4; ++j)
            bf[j] = *(const half8*)(Bs + (wn + j * 16 + l16) * 32 + quad * 8);
        for (int i = 0; i < 4; ++i)
            for (int j = 0; j < 4; ++j)
                acc[i][j] = __builtin_amdgcn_mfma_f32_16x16x32_f16(
                    af[i], bf[j], acc[i][j], 0, 0, 0);
    }

    // epilogue: C/D layout col = lane&15, row = quad*4 + reg
    // STATS path writes chunked f16: chunk = col0>>7 (constant per block).
    _Float16* Cc = (_Float16*)C + (size_t)(col0 >> 7) * M * CHUNK;
    float s[4] = {}, q[4] = {};
    for (int i = 0; i < 4; ++i) {
        for (int r = 0; r < 4; ++r) {
            int row = row0 + wm + i * 16 + quad * 4 + r;
            bool valid = row < M;
            for (int j = 0; j < 4; ++j) {
                int lcol = wn + j * 16 + l16;       // local col in 128-chunk
                float v = acc[i][j][r] + bias[col0 + lcol];
                v = v > 0.f ? v : 0.f;
                if (valid) {
                    if (STATS) {
                        Cc[(size_t)row * CHUNK + lcol] = (_Float16)v;
                        s[j] += v; q[j] += v * v;
                    } else {
                        C[(size_t)row * D + col0 + lcol] = (OutT)v;
                    }
                }
            }
        }
    }
    if (STATS) {
        for (int j = 0; j < 4; ++j) {
            float sv = s[j], qv = q[j];
            sv += __shfl_xor(sv, 16); sv += __shfl_xor(sv, 32);
            qv += __shfl_xor(qv, 16); qv += __shfl_xor(qv, 32);
            if (quad == 0) {
                int col = col0 + wn + j * 16 + l16;
                atomicAdd(&stats[col], sv);
                atomicAdd(&stats[D + col], qv);
            }
        }
    }
}

// ---------------------------------------------------------------------------
extern "C" void kernel_launch(void* const* d_in, const int* in_sizes, int n_in,
                              void* d_out, int out_size, void* d_ws, size_t ws_size,
                              hipStream_t stream) {
    const float* x_in  = (const float*)d_in[0];
    const int*   src   = (const int*)d_in[1];
    const int*   dst   = (const int*)d_in[2];
    const float* gamma = (const float*)d_in[3];
    const float* beta  = (const float*)d_in[4];
    const float* W     = (const float*)d_in[5];
    const float* b     = (const float*)d_in[6];
    float* out = (float*)d_out;

    // workspace carve-up (16B-aligned segments first)
    char* p = (char*)d_ws;
    _Float16* x16 = (_Float16*)p;  p += (size_t)N * D * 2;       // chunked [4][N][128]
    _Float16* agg = (_Float16*)p;  p += (size_t)N * D * 2;       // chunked [4][N][128]
    _Float16* Wt  = (_Float16*)p;  p += (size_t)L * D * D * 2;   // 1.57 MB
    float* src_norm = (float*)p;   p += (size_t)N * 4;
    float* dst_norm = (float*)p;   p += (size_t)N * 4;
    // contiguous zero-init region: out_deg, in_deg, stats0..2
    int* out_deg   = (int*)p;      p += (size_t)N * 4;
    int* in_deg    = (int*)p;      p += (size_t)N * 4;
    float* stats0  = (float*)p;    p += 2 * D * 4;
    float* stats1  = (float*)p;    p += 2 * D * 4;
    float* stats2  = (float*)p;    p += 2 * D * 4;
    int* csr_off   = (int*)p;      p += (size_t)(N + 1) * 4;
    int* cursor    = (int*)p;      p += (size_t)N * 4;
    int* csr_src   = (int*)p;      p += (size_t)E * 4;

    float* stats_in[3] = {stats0, stats1, stats2};

    // --- setup ---
    hipMemsetAsync(out_deg, 0, (2 * (size_t)N + 6 * D) * sizeof(int), stream);
    mega_setup<<<MEGA_BLOCKS, 256, 0, stream>>>(src, dst, x_in, W,
                                                out_deg, in_deg, x16, stats0, Wt);
    scan_indeg<<<1, 1024, 0, stream>>>(in_deg, out_deg, csr_off, cursor,
                                       src_norm, dst_norm);
    csr_fill<<<DEG_BLOCKS, 256, 0, stream>>>(src, dst, cursor, csr_src);

    dim3 mm_grid((N + 127) / 128, D / 128);
    const int agg_blocks = (N / 8) * 8;  // 10000: (node-group, chunk, sub)

    for (int l = 0; l < L; ++l) {
        const float* gl  = gamma + (size_t)l * D;
        const float* bl  = beta + (size_t)l * D;
        const _Float16* Wl = Wt + (size_t)l * D * D;
        const float* bil = b + (size_t)l * D;

        aggregate_bn<<<agg_blocks, 256, 0, stream>>>(
            x16, csr_off, csr_src, src_norm, dst_norm, stats_in[l], gl, bl, agg);
        if (l == L - 1) {
            mm_f16_relu<float, false><<<mm_grid, 256, 0, stream>>>(
                agg, Wl, bil, out, N, nullptr);
        } else {
            mm_f16_relu<_Float16, true><<<mm_grid, 256, 0, stream>>>(
                agg, Wl, bil, x16, N, stats_in[l + 1]);
        }
    }
}

// Round 9
// 283.526 us; speedup vs baseline: 1.0462x; 1.0462x over previous
//
#include <hip/hip_runtime.h>
#include <hip/hip_bf16.h>

constexpr int N = 10000;   // nodes
constexpr int D = 512;     // feature dim
constexpr int E = 160000;  // edges
constexpr int L = 3;       // layers
constexpr float EPS = 1e-5f;
constexpr int CH = 256;    // gather chunk width (cols); 2 chunks
                           // x16 layout: [2][N][256] f16. agg stays row-major.

typedef _Float16 half8 __attribute__((ext_vector_type(8)));
typedef _Float16 half4v __attribute__((ext_vector_type(4)));
typedef _Float16 half2v __attribute__((ext_vector_type(2)));
typedef float floatx4 __attribute__((ext_vector_type(4)));

// async global->LDS, 16B per lane. LDS dest = wave-uniform base + lane*16.
__device__ __forceinline__ void glds16(const _Float16* g, _Float16* l) {
    __builtin_amdgcn_global_load_lds(
        (const __attribute__((address_space(1))) uint32_t*)(g),
        (__attribute__((address_space(3))) uint32_t*)(l),
        16, 0, 0);
}

// ---------------------------------------------------------------------------
// Mega setup: degrees + x fp32->f16 (chunked) + column stats + W transpose.
// ---------------------------------------------------------------------------
constexpr int DEG_BLOCKS  = (E + 255) / 256;   // 625
constexpr int CONV_BLOCKS = 100;               // 100 rows each
constexpr int TW_BLOCKS   = L * 256;           // 768 (32x32 tiles)
constexpr int MEGA_BLOCKS = DEG_BLOCKS + CONV_BLOCKS + TW_BLOCKS;

__global__ __launch_bounds__(256) void mega_setup(
    const int* __restrict__ src, const int* __restrict__ dst,
    const float* __restrict__ x, const float* __restrict__ W,
    int* __restrict__ out_deg, int* __restrict__ in_deg,
    _Float16* __restrict__ x16, float* __restrict__ stats0,
    _Float16* __restrict__ Wt) {
    __shared__ float tb[32][33];
    int bid = blockIdx.x;
    int tid = threadIdx.x;
    if (bid < DEG_BLOCKS) {
        int e = bid * 256 + tid;
        if (e < E) {
            atomicAdd(&out_deg[src[e]], 1);
            atomicAdd(&in_deg[dst[e]], 1);
        }
    } else if (bid < DEG_BLOCKS + CONV_BLOCKS) {
        int b = bid - DEG_BLOCKS;
        int r0 = b * 100;
        int r1 = r0 + 100; if (r1 > N) r1 = N;
        int c2 = tid * 2;                 // global col pair
        int ch = c2 >> 8;                 // chunk (256-wide)
        int lc = c2 & 255;                // local col
        _Float16* xc = x16 + (size_t)ch * N * CH;
        float s0 = 0.f, s1 = 0.f, q0 = 0.f, q1 = 0.f;
        for (int r = r0; r < r1; ++r) {
            float2 v = *(const float2*)(x + (size_t)r * D + c2);
            s0 += v.x; q0 += v.x * v.x;
            s1 += v.y; q1 += v.y * v.y;
            half2v h; h[0] = (_Float16)v.x; h[1] = (_Float16)v.y;
            *(half2v*)(xc + (size_t)r * CH + lc) = h;
        }
        atomicAdd(&stats0[c2], s0);
        atomicAdd(&stats0[c2 + 1], s1);
        atomicAdd(&stats0[D + c2], q0);
        atomicAdd(&stats0[D + c2 + 1], q1);
    } else {
        int b = bid - DEG_BLOCKS - CONV_BLOCKS;  // 0..767
        int l = b >> 8;
        int t = b & 255;
        int k0 = (t >> 4) * 32, n0 = (t & 15) * 32;
        int tx = tid & 31, ty = tid >> 5;  // 32 x 8
        const float* Wl = W + (size_t)l * D * D;
        _Float16* Wtl = Wt + (size_t)l * D * D;
        for (int i = 0; i < 32; i += 8)
            tb[ty + i][tx] = Wl[(size_t)(k0 + ty + i) * D + n0 + tx];
        __syncthreads();
        for (int i = 0; i < 32; i += 8)
            Wtl[(size_t)(n0 + ty + i) * D + k0 + tx] = (_Float16)tb[tx][ty + i];
    }
}

// ---------------------------------------------------------------------------
// Single block: exclusive scan of in_deg -> off & cursor, plus both norms.
// ---------------------------------------------------------------------------
__global__ void scan_indeg(const int* __restrict__ in_deg,
                           const int* __restrict__ out_deg,
                           int* __restrict__ off, int* __restrict__ cursor,
                           float* __restrict__ src_norm, float* __restrict__ dst_norm) {
    __shared__ int lsum[1024];
    int t = threadIdx.x;
    const int chunk = (N + 1023) / 1024;
    int start = t * chunk;
    int end = start + chunk; if (end > N) end = N;
    int s = 0;
    for (int i = start; i < end; ++i) s += in_deg[i];
    lsum[t] = s;
    __syncthreads();
    for (int d = 1; d < 1024; d <<= 1) {
        int v = (t >= d) ? lsum[t - d] : 0;
        __syncthreads();
        lsum[t] += v;
        __syncthreads();
    }
    int excl = (t == 0) ? 0 : lsum[t - 1];
    for (int i = start; i < end; ++i) {
        off[i] = excl;
        cursor[i] = excl;
        excl += in_deg[i];
        int od = out_deg[i]; if (od < 1) od = 1;
        int id = in_deg[i];  if (id < 1) id = 1;
        src_norm[i] = rsqrtf((float)od);
        dst_norm[i] = rsqrtf((float)id);
    }
    if (t == 1023) off[N] = lsum[1023];
}

__global__ void csr_fill(const int* __restrict__ src, const int* __restrict__ dst,
                         int* __restrict__ cursor, int* __restrict__ csr_src) {
    int e = blockIdx.x * blockDim.x + threadIdx.x;
    if (e >= E) return;
    int d = dst[e];
    int pos = atomicAdd(&cursor[d], 1);
    csr_src[pos] = src[e];
}

// ---------------------------------------------------------------------------
// Fused BN + gather-aggregate, temporally chunked.
// Grid: 5000 blocks, chunk-major: blocks [0,2500) do chunk 0 (cols 0..255)
// for all nodes, blocks [2500,5000) do chunk 1. During each phase every
// XCD's L2 sees the same 5 MB chunk -> ~80% hit without any XCD-mapping
// assumption. Wave handles one (node, chunk): 4 cols/lane (8B dwordx2).
// x16 chunked [2][N][256]; agg written row-major.
// ---------------------------------------------------------------------------
__global__ __launch_bounds__(256) void aggregate_bn(
    const _Float16* __restrict__ x, const int* __restrict__ off,
    const int* __restrict__ csr_src, const float* __restrict__ src_norm,
    const float* __restrict__ dst_norm, const float* __restrict__ stats,
    const float* __restrict__ gamma, const float* __restrict__ beta,
    _Float16* __restrict__ agg) {
    int bid = blockIdx.x;
    int ch = bid >= 2500;
    int bb = ch ? bid - 2500 : bid;
    int wave = threadIdx.x >> 6;
    int lane = threadIdx.x & 63;
    int n = bb * 4 + wave;           // 2500*4 = 10000 exact
    int lc = lane * 4;               // local col in chunk
    int gc = ch * CH + lc;           // global col

    const _Float16* xc = x + (size_t)ch * N * CH;

    float scale[4], shift[4];
    const float invN = 1.0f / (float)N;
    for (int i = 0; i < 4; ++i) {
        int c = gc + i;
        float mu = stats[c] * invN;
        float var = stats[D + c] * invN - mu * mu;
        float sc = gamma[c] * rsqrtf(var + EPS);
        scale[i] = sc;
        shift[i] = beta[c] - mu * sc;
    }

    int e0 = off[n], e1 = off[n + 1];
    float a[4] = {}, a2[4] = {};
    float t = 0.f;
    int e = e0;
    for (; e + 4 <= e1; e += 4) {
        int s0 = csr_src[e];
        int s1 = csr_src[e + 1];
        int s2 = csr_src[e + 2];
        int s3 = csr_src[e + 3];
        float n0 = src_norm[s0];
        float n1 = src_norm[s1];
        float n2 = src_norm[s2];
        float n3 = src_norm[s3];
        half4v v0 = *(const half4v*)(xc + (size_t)s0 * CH + lc);
        half4v v1 = *(const half4v*)(xc + (size_t)s1 * CH + lc);
        half4v v2 = *(const half4v*)(xc + (size_t)s2 * CH + lc);
        half4v v3 = *(const half4v*)(xc + (size_t)s3 * CH + lc);
        t += (n0 + n1) + (n2 + n3);
        for (int k = 0; k < 4; ++k) {
            a[k]  += (float)v0[k] * n0;
            a2[k] += (float)v1[k] * n1;
            a[k]  += (float)v2[k] * n2;
            a2[k] += (float)v3[k] * n3;
        }
    }
    for (; e < e1; ++e) {
        int s0 = csr_src[e];
        float n0 = src_norm[s0];
        half4v v0 = *(const half4v*)(xc + (size_t)s0 * CH + lc);
        t += n0;
        for (int k = 0; k < 4; ++k) a[k] += (float)v0[k] * n0;
    }
    float dn = dst_norm[n];
    half4v o;
    for (int i = 0; i < 4; ++i)
        o[i] = (_Float16)(dn * (scale[i] * (a[i] + a2[i]) + shift[i] * t));
    *(half4v*)(agg + (size_t)n * D + gc) = o;  // row-major output
}

// ---------------------------------------------------------------------------
// C = relu(A @ W + bias) via f16 MFMA with global_load_lds staging.
// A: M x 512 f16 row-major (agg).  Bt[n][k] = W[k][n] f16.
// Block 256 = 4 waves; tile 128(M) x 128(N); BK=32.
// STATS=true: write x16-next CHUNKED [2][M][256] + next-layer stats.
// STATS=false: write row-major OutT.
// ---------------------------------------------------------------------------
template <typename OutT, bool STATS>
__global__ __launch_bounds__(256) void mm_f16_relu(
    const _Float16* __restrict__ A, const _Float16* __restrict__ Bt,
    const float* __restrict__ bias, OutT* __restrict__ C, int M,
    float* __restrict__ stats) {
    __shared__ __align__(16) _Float16 As[128 * 32];
    __shared__ __align__(16) _Float16 Bs[128 * 32];
    const int tid  = threadIdx.x;
    const int wave = tid >> 6;
    const int lane = tid & 63;
    const int quad = lane >> 4;
    const int l16  = lane & 15;
    const int row0 = blockIdx.x * 128;
    const int col0 = blockIdx.y * 128;
    const int wm = (wave & 1) * 64;
    const int wn = (wave >> 1) * 64;
    const int sr = lane >> 2;
    const int sc = (lane & 3) * 8;

    int ar0 = row0 + wave * 32 + sr;
    int ar1 = ar0 + 16;
    if (ar0 >= M) ar0 = M - 1;
    if (ar1 >= M) ar1 = M - 1;
    const _Float16* gA0 = A + (size_t)ar0 * D + sc;
    const _Float16* gA1 = A + (size_t)ar1 * D + sc;
    const _Float16* gB0 = Bt + (size_t)(col0 + wave * 32 + sr) * D + sc;
    const _Float16* gB1 = Bt + (size_t)(col0 + wave * 32 + 16 + sr) * D + sc;
    _Float16* lA0 = As + (wave * 32) * 32;
    _Float16* lA1 = As + (wave * 32 + 16) * 32;
    _Float16* lB0 = Bs + (wave * 32) * 32;
    _Float16* lB1 = Bs + (wave * 32 + 16) * 32;

    floatx4 acc[4][4] = {};

    for (int k0 = 0; k0 < D; k0 += 32) {
        __syncthreads();
        glds16(gA0 + k0, lA0);
        glds16(gA1 + k0, lA1);
        glds16(gB0 + k0, lB0);
        glds16(gB1 + k0, lB1);
        __syncthreads();  // compiler inserts vmcnt(0) drain here
        half8 af[4], bf[4];
        for (int i = 0; i < 4; ++i)
            af[i] = *(const half8*)(As + (wm + i * 16 + l16) * 32 + quad * 8);
        for (int j = 0; j < 4; ++j)
            bf[j] = *(const half8*)(Bs + (wn + j * 16 + l16) * 32 + quad * 8);
        for (int i = 0; i < 4; ++i)
            for (int j = 0; j < 4; ++j)
                acc[i][j] = __builtin_amdgcn_mfma_f32_16x16x32_f16(
                    af[i], bf[j], acc[i][j], 0, 0, 0);
    }

    // epilogue: C/D layout col = lane&15, row = quad*4 + reg
    // STATS path writes x16 chunked: chunk = col0>>8 (constant per block).
    _Float16* Cc = (_Float16*)C + (size_t)(col0 >> 8) * M * CH;
    float s[4] = {}, q[4] = {};
    for (int i = 0; i < 4; ++i) {
        for (int r = 0; r < 4; ++r) {
            int row = row0 + wm + i * 16 + quad * 4 + r;
            bool valid = row < M;
            for (int j = 0; j < 4; ++j) {
                int col = col0 + wn + j * 16 + l16;
                float v = acc[i][j][r] + bias[col];
                v = v > 0.f ? v : 0.f;
                if (valid) {
                    if (STATS) {
                        Cc[(size_t)row * CH + (col & 255)] = (_Float16)v;
                        s[j] += v; q[j] += v * v;
                    } else {
                        C[(size_t)row * D + col] = (OutT)v;
                    }
                }
            }
        }
    }
    if (STATS) {
        for (int j = 0; j < 4; ++j) {
            float sv = s[j], qv = q[j];
            sv += __shfl_xor(sv, 16); sv += __shfl_xor(sv, 32);
            qv += __shfl_xor(qv, 16); qv += __shfl_xor(qv, 32);
            if (quad == 0) {
                int col = col0 + wn + j * 16 + l16;
                atomicAdd(&stats[col], sv);
                atomicAdd(&stats[D + col], qv);
            }
        }
    }
}

// ---------------------------------------------------------------------------
extern "C" void kernel_launch(void* const* d_in, const int* in_sizes, int n_in,
                              void* d_out, int out_size, void* d_ws, size_t ws_size,
                              hipStream_t stream) {
    const float* x_in  = (const float*)d_in[0];
    const int*   src   = (const int*)d_in[1];
    const int*   dst   = (const int*)d_in[2];
    const float* gamma = (const float*)d_in[3];
    const float* beta  = (const float*)d_in[4];
    const float* W     = (const float*)d_in[5];
    const float* b     = (const float*)d_in[6];
    float* out = (float*)d_out;

    // workspace carve-up (16B-aligned segments first)
    char* p = (char*)d_ws;
    _Float16* x16 = (_Float16*)p;  p += (size_t)N * D * 2;       // chunked [2][N][256]
    _Float16* agg = (_Float16*)p;  p += (size_t)N * D * 2;       // row-major
    _Float16* Wt  = (_Float16*)p;  p += (size_t)L * D * D * 2;   // 1.57 MB
    float* src_norm = (float*)p;   p += (size_t)N * 4;
    float* dst_norm = (float*)p;   p += (size_t)N * 4;
    // contiguous zero-init region: out_deg, in_deg, stats0..2
    int* out_deg   = (int*)p;      p += (size_t)N * 4;
    int* in_deg    = (int*)p;      p += (size_t)N * 4;
    float* stats0  = (float*)p;    p += 2 * D * 4;
    float* stats1  = (float*)p;    p += 2 * D * 4;
    float* stats2  = (float*)p;    p += 2 * D * 4;
    int* csr_off   = (int*)p;      p += (size_t)(N + 1) * 4;
    int* cursor    = (int*)p;      p += (size_t)N * 4;
    int* csr_src   = (int*)p;      p += (size_t)E * 4;

    float* stats_in[3] = {stats0, stats1, stats2};

    // --- setup ---
    hipMemsetAsync(out_deg, 0, (2 * (size_t)N + 6 * D) * sizeof(int), stream);
    mega_setup<<<MEGA_BLOCKS, 256, 0, stream>>>(src, dst, x_in, W,
                                                out_deg, in_deg, x16, stats0, Wt);
    scan_indeg<<<1, 1024, 0, stream>>>(in_deg, out_deg, csr_off, cursor,
                                       src_norm, dst_norm);
    csr_fill<<<DEG_BLOCKS, 256, 0, stream>>>(src, dst, cursor, csr_src);

    dim3 mm_grid((N + 127) / 128, D / 128);
    const int agg_blocks = 5000;  // 2500 per chunk, chunk-major order

    for (int l = 0; l < L; ++l) {
        const float* gl  = gamma + (size_t)l * D;
        const float* bl  = beta + (size_t)l * D;
        const _Float16* Wl = Wt + (size_t)l * D * D;
        const float* bil = b + (size_t)l * D;

        aggregate_bn<<<agg_blocks, 256, 0, stream>>>(
            x16, csr_off, csr_src, src_norm, dst_norm, stats_in[l], gl, bl, agg);
        if (l == L - 1) {
            mm_f16_relu<float, false><<<mm_grid, 256, 0, stream>>>(
                agg, Wl, bil, out, N, nullptr);
        } else {
            mm_f16_relu<_Float16, true><<<mm_grid, 256, 0, stream>>>(
                agg, Wl, bil, x16, N, stats_in[l + 1]);
        }
    }
}